// Round 7
// baseline (7108.897 us; speedup 1.0000x reference)
//
#include <hip/hip_runtime.h>
#include <hip/hip_bf16.h>

// BeamDecoder: greedy CVRP-style decode.
// s_i(step) = c*( G[last,i] + (load/cap)*u_i )   (v==0 since bq==0; folded)
// R7: per-CU miss-concurrency (~48 lines) limits the row fetch (R6 falsified
// per-wave theory). Halve lines: bf16 RN plane of G (4 KB/row) for the scan;
// window-certified argmax (count of candidates within W=2E of max; E from
// per-row gmax). cnt==1 -> winner exact; cnt>=2 -> fallback exact fp32 row +
// R5-verbatim scan. Scores computed exactly in a deferred parallel pass
// (fmaf(u,lr,g_exact)*C0, identical expression to R3-R6). Single wave, no
// barriers in the step loop.

#define NN 2048
#define HH 1024
#define TSTEPS (NN + NN / 8)   // 2304
#define TILE 64
#define KT 16

// ---------------- pack Wq[:, :H] into ld=1024 buffer ----------------
__global__ __launch_bounds__(256) void prep_wqh(const float* __restrict__ Wq,
                                                float* __restrict__ Wqh) {
  int id = blockIdx.x * 256 + threadIdx.x;
  int r = id >> 10, c = id & 1023;
  Wqh[id] = Wq[r * (HH + 2) + c];
}

// ---------------- NT GEMM: C[M,N] = A[M,K] @ B[N,K]^T (+ bias[n]) ----------------
__global__ __launch_bounds__(256) void gemm_nt(const float* __restrict__ A, int lda,
                                               const float* __restrict__ B, int ldb,
                                               float* __restrict__ C, int ldc,
                                               int K, const float* __restrict__ bias) {
  __shared__ float As[KT][TILE + 4];
  __shared__ float Bs[KT][TILE + 4];
  const int i0 = blockIdx.y * TILE;
  const int j0 = blockIdx.x * TILE;
  const int t = threadIdx.x;
  const int srow = t >> 2, sq = t & 3;
  const int tx = t & 15, ty = t >> 4;
  float acc[4][4] = {};
  for (int k0 = 0; k0 < K; k0 += KT) {
    float4 av = *(const float4*)&A[(size_t)(i0 + srow) * lda + k0 + sq * 4];
    float4 bv = *(const float4*)&B[(size_t)(j0 + srow) * ldb + k0 + sq * 4];
    __syncthreads();
    As[sq * 4 + 0][srow] = av.x; As[sq * 4 + 1][srow] = av.y;
    As[sq * 4 + 2][srow] = av.z; As[sq * 4 + 3][srow] = av.w;
    Bs[sq * 4 + 0][srow] = bv.x; Bs[sq * 4 + 1][srow] = bv.y;
    Bs[sq * 4 + 2][srow] = bv.z; Bs[sq * 4 + 3][srow] = bv.w;
    __syncthreads();
#pragma unroll
    for (int k = 0; k < KT; ++k) {
      float4 a4 = *(const float4*)&As[k][ty * 4];
      float4 b4 = *(const float4*)&Bs[k][tx * 4];
      float a[4] = {a4.x, a4.y, a4.z, a4.w};
      float b[4] = {b4.x, b4.y, b4.z, b4.w};
#pragma unroll
      for (int m = 0; m < 4; ++m)
#pragma unroll
        for (int n = 0; n < 4; ++n) acc[m][n] = fmaf(a[m], b[n], acc[m][n]);
    }
  }
  float bb[4] = {0.f, 0.f, 0.f, 0.f};
  if (bias) {
#pragma unroll
    for (int n = 0; n < 4; ++n) bb[n] = bias[j0 + tx * 4 + n];
  }
#pragma unroll
  for (int m = 0; m < 4; ++m) {
    float4 st = {acc[m][0] + bb[0], acc[m][1] + bb[1], acc[m][2] + bb[2], acc[m][3] + bb[3]};
    *(float4*)&C[(size_t)(i0 + ty * 4 + m) * ldc + j0 + tx * 4] = st;
  }
}

// ---------------- u_i = K_i . Wq[:,H], v_i = K_i . bq  (one wave per row) ---------
__global__ __launch_bounds__(64) void uv_k(const float* __restrict__ Kmat,
                                           const float* __restrict__ Wq,
                                           const float* __restrict__ bq,
                                           float* __restrict__ u, float* __restrict__ v) {
  int i = blockIdx.x;
  int lane = threadIdx.x;
  float su = 0.f, sv = 0.f;
#pragma unroll
  for (int m = 0; m < HH / 64; ++m) {
    int j = lane + 64 * m;
    float kv = Kmat[(size_t)i * HH + j];
    su = fmaf(kv, Wq[(size_t)j * (HH + 2) + HH], su);
    sv = fmaf(kv, bq[j], sv);
  }
#pragma unroll
  for (int off = 32; off; off >>= 1) {
    su += __shfl_down(su, off, 64);
    sv += __shfl_down(sv, off, 64);
  }
  if (lane == 0) { u[i] = su; v[i] = sv; }
}

// ---------------- umax = max |u| ----------------
__global__ __launch_bounds__(256) void umax_k(const float* __restrict__ u,
                                              float* __restrict__ umaxp) {
  __shared__ float sm[256];
  int t = threadIdx.x;
  float m = 0.f;
  for (int i = t; i < NN; i += 256) m = fmaxf(m, fabsf(u[i]));
  sm[t] = m;
  __syncthreads();
  for (int s = 128; s; s >>= 1) {
    if (t < s) sm[t] = fmaxf(sm[t], sm[t + s]);
    __syncthreads();
  }
  if (t == 0) *umaxp = sm[0];
}

// ---------------- bf16 RN plane of GT + per-row max|g| ----------------
__device__ __forceinline__ unsigned short f2bf_rn(float f) {
  unsigned x = __float_as_uint(f);
  unsigned r = ((x >> 16) & 1u) + 0x7fffu;   // round-to-nearest-even
  return (unsigned short)((x + r) >> 16);
}
__global__ __launch_bounds__(256) void bf16_plane(const float* __restrict__ GT,
                                                  unsigned short* __restrict__ Gb,
                                                  float* __restrict__ gmax) {
  __shared__ float sm[256];
  const int row = blockIdx.x, t = threadIdx.x;
  const float* rp = GT + (size_t)row * NN + 8 * t;
  float4 a = *(const float4*)rp;
  float4 b = *(const float4*)(rp + 4);
  float f[8] = {a.x, a.y, a.z, a.w, b.x, b.y, b.z, b.w};
  unsigned pk[4];
#pragma unroll
  for (int q = 0; q < 4; ++q)
    pk[q] = (unsigned)f2bf_rn(f[2 * q]) | ((unsigned)f2bf_rn(f[2 * q + 1]) << 16);
  *(uint4*)(Gb + (size_t)row * NN + 8 * t) = make_uint4(pk[0], pk[1], pk[2], pk[3]);
  float m = 0.f;
#pragma unroll
  for (int q = 0; q < 8; ++q) m = fmaxf(m, fabsf(f[q]));
  sm[t] = m;
  __syncthreads();
  for (int s = 128; s; s >>= 1) {
    if (t < s) sm[t] = fmaxf(sm[t], sm[t + s]);
    __syncthreads();
  }
  if (t == 0) gmax[row] = sm[0];
}

// DPP merge of (bv,bi): max value, smallest index on ties. Invalid lanes get
// (-inf, INT_MAX).
#define DPP_MERGE2(CTRL)                                                      \
  {                                                                           \
    int ovb = __builtin_amdgcn_update_dpp(                                    \
        (int)0xFF800000, __float_as_int(bv), (CTRL), 0xf, 0xf, false);        \
    int oib = __builtin_amdgcn_update_dpp(                                    \
        0x7fffffff, bi, (CTRL), 0xf, 0xf, false);                             \
    float ov = __int_as_float(ovb);                                           \
    if (ov > bv || (ov == bv && oib < bi)) { bv = ov; bi = oib; }             \
  }

// DPP merge of (bv,bi,cc): additionally counts elements within W of the
// running max (window merge: never undercounts the true candidate set).
#define DPP_MERGE3(CTRL)                                                      \
  {                                                                           \
    int ovb = __builtin_amdgcn_update_dpp(                                    \
        (int)0xFF800000, __float_as_int(bv), (CTRL), 0xf, 0xf, false);        \
    int oib = __builtin_amdgcn_update_dpp(                                    \
        0x7fffffff, bi, (CTRL), 0xf, 0xf, false);                             \
    int occ = __builtin_amdgcn_update_dpp(0, cc, (CTRL), 0xf, 0xf, false);    \
    float ov = __int_as_float(ovb);                                           \
    float hi = fmaxf(bv, ov), lo = fminf(bv, ov);                             \
    int cwin = (hi - lo <= W) ? (cc + occ) : ((ov > bv) ? occ : cc);          \
    if (ov > bv || (ov == bv && oib < bi)) { bv = ov; bi = oib; }             \
    cc = cwin;                                                                \
  }

// ---------------- sequential decode: ONE wave, 64 lanes, 32 nodes/lane -----------
// Lane owns nodes 8c..8c+7 for c = r*64+lane, r=0..3 (64 B bf16 per lane).
__global__ __launch_bounds__(64, 1) void decode(const float* __restrict__ GT,
                                                const unsigned* __restrict__ GbU,
                                                const float* __restrict__ gmaxp,
                                                const float* __restrict__ umaxp,
                                                const float* __restrict__ u,
                                                const float* __restrict__ demands,
                                                const int* __restrict__ capp,
                                                const int* __restrict__ depotp,
                                                float* __restrict__ out) {
  __shared__ __align__(16) float s_dem[NN];      // raw demands
  __shared__ __align__(16) float s_dd[NN];       // demands, +inf when visited
  __shared__ __align__(16) unsigned s_drowb[NN / 2];  // bf16 depot row
  __shared__ __align__(16) float s_tour[TSTEPS + 1];
  __shared__ __align__(16) float s_lr[TSTEPS];   // lr per step; -1 => score 0

  const int lane = threadIdx.x;
  const int depot = *depotp;
  const float capf = (float)(*capp);
  const float umaxv = *umaxp;
  const float INF = __builtin_inff();
  const float NEGINF = -INF;
  const float C0 = 0.015625f;  // ALPHA / sqrt(HID), exact power of two

  for (int i = lane; i < NN; i += 64) {
    float d = demands[i];
    s_dem[i] = d;
    s_dd[i] = d;
  }
  for (int i = lane; i < NN / 2; i += 64)
    s_drowb[i] = GbU[(size_t)depot * (NN / 2) + i];
  const float gmxd = gmaxp[depot];
  __syncthreads();
  if (lane == 0) {
    s_dd[depot] = INF;
    s_tour[0] = (float)depot;
  }

  float uu[32];
#pragma unroll
  for (int r = 0; r < 4; ++r) {
    int c = r * 64 + lane;
    float4 a = ((const float4*)u)[2 * c];
    float4 b = ((const float4*)u)[2 * c + 1];
    uu[r * 8 + 0] = a.x; uu[r * 8 + 1] = a.y; uu[r * 8 + 2] = a.z; uu[r * 8 + 3] = a.w;
    uu[r * 8 + 4] = b.x; uu[r * 8 + 5] = b.y; uu[r * 8 + 6] = b.z; uu[r * 8 + 7] = b.w;
  }

  const float4* dd4 = (const float4*)s_dd;
  const uint4* drb4 = (const uint4*)s_drowb;

  int done = 0, ntaken = 0, lasts = depot;
  float load = capf;
  float lr = load / capf;  // same fp32 division as reference
  // window bound: 2E + slack, E <= gmax*2^-8 (bf16 RN) + fma epsilon
  float gmx = gmxd;
  float W = fmaf(gmx, 0.0079f, (gmx + umaxv) * 2e-6f + 1e-6f);
  uint4 gb[4];
#pragma unroll
  for (int r = 0; r < 4; ++r) gb[r] = drb4[r * 64 + lane];

  for (int step = 0; step < TSTEPS; ++step) {
    if (done) {  // ref emits (depot, 0) forever once done
      const float df = (float)depot;
      for (int q = step + lane; q < TSTEPS; q += 64) {
        s_tour[1 + q] = df;
        s_lr[q] = -1.0f;
      }
      break;
    }
    // ---- approx scan over 32 nodes from bf16 plane (err <= E per element)
    float bv = NEGINF;
    int bi = 0x7fffffff;
    int cc = 0;
#pragma unroll
    for (int r = 0; r < 4; ++r) {
      const int c = r * 64 + lane;
      float4 da = dd4[2 * c];
      float4 db = dd4[2 * c + 1];
      float dl[8] = {da.x, da.y, da.z, da.w, db.x, db.y, db.z, db.w};
      unsigned wv[4] = {gb[r].x, gb[r].y, gb[r].z, gb[r].w};
#pragma unroll
      for (int q = 0; q < 4; ++q) {
#pragma unroll
        for (int h = 0; h < 2; ++h) {
          int k = 2 * q + h;
          float g = __uint_as_float(h ? (wv[q] & 0xffff0000u) : (wv[q] << 16));
          float tt = fmaf(uu[r * 8 + k], lr, g);
          bool feas = (dl[k] <= load);
          if (feas) {
            if (tt > bv) { cc = (tt - bv <= W) ? (cc + 1) : 1; bv = tt; bi = 8 * c + k; }
            else if (bv - tt <= W) cc += 1;
          }
        }
      }
    }
    DPP_MERGE3(0x111); DPP_MERGE3(0x112); DPP_MERGE3(0x114);
    DPP_MERGE3(0x118); DPP_MERGE3(0x142); DPP_MERGE3(0x143);
    int cnt = __builtin_amdgcn_readlane(cc, 63);
    int rbi = __builtin_amdgcn_readlane(bi, 63);

    int take, nxt;
    if (cnt == 0) {          // no feasible node (certified exactly)
      take = 0; nxt = depot;
    } else if (cnt == 1) {   // unique candidate == exact argmax (certified)
      take = 1; nxt = rbi;
    } else {
      // ---- fallback: exact fp32 row + R5-verbatim exact scan
      const float4* erow = (const float4*)(GT + (size_t)lasts * NN);
      float bv = NEGINF;
      int bi = NN;
#pragma unroll
      for (int r = 0; r < 4; ++r) {
        const int c = r * 64 + lane;
        float4 ea = erow[2 * c];
        float4 eb = erow[2 * c + 1];
        float4 da = dd4[2 * c];
        float4 db = dd4[2 * c + 1];
        float gl[8] = {ea.x, ea.y, ea.z, ea.w, eb.x, eb.y, eb.z, eb.w};
        float dl[8] = {da.x, da.y, da.z, da.w, db.x, db.y, db.z, db.w};
#pragma unroll
        for (int k = 0; k < 8; ++k) {  // ascending node order: first-max
          float tt = fmaf(uu[r * 8 + k], lr, gl[k]);
          bool feas = (dl[k] <= load);
          if (feas && tt > bv) { bv = tt; bi = 8 * c + k; }
        }
      }
      DPP_MERGE2(0x111); DPP_MERGE2(0x112); DPP_MERGE2(0x114);
      DPP_MERGE2(0x118); DPP_MERGE2(0x142); DPP_MERGE2(0x143);
      float rbv = __int_as_float(__builtin_amdgcn_readlane(__float_as_int(bv), 63));
      rbi = __builtin_amdgcn_readlane(bi, 63);
      take = (rbv > NEGINF);
      nxt = take ? rbi : depot;
    }

    // ---- prefetch next bf16 row + its gmax FIRST (bookkeeping hides under it)
    if (nxt == depot) {
#pragma unroll
      for (int r = 0; r < 4; ++r) gb[r] = drb4[r * 64 + lane];
      gmx = gmxd;
    } else {
      const uint4* rowb = (const uint4*)(GbU + (size_t)nxt * (NN / 2));
#pragma unroll
      for (int r = 0; r < 4; ++r) gb[r] = rowb[r * 64 + lane];
      gmx = gmaxp[nxt];
    }

    // ---- state update + LDS-buffered outputs
    if (lane == 0) {
      s_tour[1 + step] = (float)nxt;
      s_lr[step] = take ? lr : -1.0f;  // lr used THIS step (for deferred score)
    }
    if (take) {
      load = load - s_dem[rbi];  // same fp32 op sequence as reference
      ntaken++;
      if (lane == 0) s_dd[rbi] = INF;
    } else {
      load = capf;
      if (ntaken == NN - 1) done = 1;
    }
    lasts = nxt;
    lr = load / capf;  // same fp32 division as reference
    W = fmaf(gmx, 0.0079f, (gmx + umaxv) * 2e-6f + 1e-6f);
  }

  // ---- flush tour; compute scores exactly in parallel (off-chain)
  for (int i = lane; i <= TSTEPS; i += 64) out[i] = s_tour[i];
  for (int s = lane; s < TSTEPS; s += 64) {
    float lrs = s_lr[s];
    float sc = 0.0f;
    if (lrs >= 0.0f) {
      int lastI = (int)s_tour[s];
      int biI = (int)s_tour[s + 1];
      float g = GT[(size_t)lastI * NN + biI];
      sc = fmaf(u[biI], lrs, g) * C0;  // identical expression to R3-R6
    }
    out[1 + TSTEPS + s] = sc;
  }
}

extern "C" void kernel_launch(void* const* d_in, const int* in_sizes, int n_in,
                              void* d_out, int out_size, void* d_ws, size_t ws_size,
                              hipStream_t stream) {
  const float* emb     = (const float*)d_in[0];  // [N, H]
  const float* demands = (const float*)d_in[1];  // [N]
  const float* Wq      = (const float*)d_in[2];  // [H, H+2]
  const float* bq      = (const float*)d_in[3];  // [H]
  const float* Wk      = (const float*)d_in[4];  // [H, H]
  const float* bk      = (const float*)d_in[5];  // [H]
  const int* cap       = (const int*)d_in[6];
  const int* depot     = (const int*)d_in[7];
  float* out           = (float*)d_out;          // 2305 tour + 2304 scores, fp32

  char* ws = (char*)d_ws;
  float* Kmat = (float*)(ws);                         // 8 MB  [N,H]
  float* Z    = (float*)(ws + ((size_t)8 << 20));     // 8 MB  [N,H]; reused as Gb
  float* GT   = (float*)(ws + ((size_t)16 << 20));    // 16 MB [N,N] row=last, +v
  float* Wqh  = (float*)(ws + ((size_t)32 << 20));    // 4 MB  [H,H]
  float* u    = (float*)(ws + ((size_t)36 << 20));    // 8 KB
  float* v    = (float*)(ws + ((size_t)36 << 20) + 8192);
  float* gmax = (float*)(ws + ((size_t)36 << 20) + 16384);
  float* umax = (float*)(ws + ((size_t)36 << 20) + 24576);
  unsigned short* Gb = (unsigned short*)Z;            // 8 MB bf16 plane (Z dead)

  hipLaunchKernelGGL(prep_wqh, dim3(4096), dim3(256), 0, stream, Wq, Wqh);
  // K = emb @ Wk^T + bk
  hipLaunchKernelGGL(gemm_nt, dim3(HH / TILE, NN / TILE), dim3(256), 0, stream,
                     emb, HH, Wk, HH, Kmat, HH, HH, bk);
  // Z = emb @ Wqh^T
  hipLaunchKernelGGL(gemm_nt, dim3(HH / TILE, NN / TILE), dim3(256), 0, stream,
                     emb, HH, Wqh, HH, Z, HH, HH, (const float*)nullptr);
  // u_i = K_i . Wq[:,H], v_i = K_i . bq
  hipLaunchKernelGGL(uv_k, dim3(NN), dim3(64), 0, stream, Kmat, Wq, bq, u, v);
  hipLaunchKernelGGL(umax_k, dim3(1), dim3(256), 0, stream, u, umax);
  // GT = Z @ K^T + v (v==0 since bq==0 -> bit-identical)
  hipLaunchKernelGGL(gemm_nt, dim3(NN / TILE, NN / TILE), dim3(256), 0, stream,
                     Z, HH, Kmat, HH, GT, NN, HH, v);
  // bf16 plane + per-row gmax (Z is dead after the GT GEMM; Gb overlays it)
  hipLaunchKernelGGL(bf16_plane, dim3(NN), dim3(256), 0, stream, GT, Gb, gmax);
  hipLaunchKernelGGL(decode, dim3(1), dim3(64), 0, stream, GT, (const unsigned*)Gb,
                     gmax, umax, u, demands, cap, depot, out);
}

// Round 8
// 2405.982 us; speedup vs baseline: 2.9547x; 2.9547x over previous
//
#include <hip/hip_runtime.h>
#include <hip/hip_bf16.h>

// BeamDecoder: greedy CVRP-style decode.
// s_i(step) = c*( G[last,i] + (load/cap)*u_i )   (v==0 since bq==0; folded)
// R8: R7's window-certified bf16 plane regressed (certifier too conservative,
// fallback ~always, serial double-load). Revert to R5 chain + NEW lever:
// per-row static top-256 candidates by g (exact radix-select, fp32 bit-copies)
// = 2 KB/row (16 lines vs 64). Winner among candidates with
// t > thr + lr*umax + 0.5 is provably the global argmax (outside nodes have
// g <= thr, |u| <= umax; 0.5 >> all fp32 rounding). Else fallback = verbatim
// R5 full-row scan (~5-10% of steps: route ends, late decode). Scores exact
// via deferred pass (same fmaf(u,lr,g)*C0 expression as R3-R7).

#define NN 2048
#define HH 1024
#define TSTEPS (NN + NN / 8)   // 2304
#define TILE 64
#define KT 16
#define KCAND 256

// ---------------- pack Wq[:, :H] into ld=1024 buffer ----------------
__global__ __launch_bounds__(256) void prep_wqh(const float* __restrict__ Wq,
                                                float* __restrict__ Wqh) {
  int id = blockIdx.x * 256 + threadIdx.x;
  int r = id >> 10, c = id & 1023;
  Wqh[id] = Wq[r * (HH + 2) + c];
}

// ---------------- NT GEMM: C[M,N] = A[M,K] @ B[N,K]^T (+ bias[n]) ----------------
__global__ __launch_bounds__(256) void gemm_nt(const float* __restrict__ A, int lda,
                                               const float* __restrict__ B, int ldb,
                                               float* __restrict__ C, int ldc,
                                               int K, const float* __restrict__ bias) {
  __shared__ float As[KT][TILE + 4];
  __shared__ float Bs[KT][TILE + 4];
  const int i0 = blockIdx.y * TILE;
  const int j0 = blockIdx.x * TILE;
  const int t = threadIdx.x;
  const int srow = t >> 2, sq = t & 3;
  const int tx = t & 15, ty = t >> 4;
  float acc[4][4] = {};
  for (int k0 = 0; k0 < K; k0 += KT) {
    float4 av = *(const float4*)&A[(size_t)(i0 + srow) * lda + k0 + sq * 4];
    float4 bv = *(const float4*)&B[(size_t)(j0 + srow) * ldb + k0 + sq * 4];
    __syncthreads();
    As[sq * 4 + 0][srow] = av.x; As[sq * 4 + 1][srow] = av.y;
    As[sq * 4 + 2][srow] = av.z; As[sq * 4 + 3][srow] = av.w;
    Bs[sq * 4 + 0][srow] = bv.x; Bs[sq * 4 + 1][srow] = bv.y;
    Bs[sq * 4 + 2][srow] = bv.z; Bs[sq * 4 + 3][srow] = bv.w;
    __syncthreads();
#pragma unroll
    for (int k = 0; k < KT; ++k) {
      float4 a4 = *(const float4*)&As[k][ty * 4];
      float4 b4 = *(const float4*)&Bs[k][tx * 4];
      float a[4] = {a4.x, a4.y, a4.z, a4.w};
      float b[4] = {b4.x, b4.y, b4.z, b4.w};
#pragma unroll
      for (int m = 0; m < 4; ++m)
#pragma unroll
        for (int n = 0; n < 4; ++n) acc[m][n] = fmaf(a[m], b[n], acc[m][n]);
    }
  }
  float bb[4] = {0.f, 0.f, 0.f, 0.f};
  if (bias) {
#pragma unroll
    for (int n = 0; n < 4; ++n) bb[n] = bias[j0 + tx * 4 + n];
  }
#pragma unroll
  for (int m = 0; m < 4; ++m) {
    float4 st = {acc[m][0] + bb[0], acc[m][1] + bb[1], acc[m][2] + bb[2], acc[m][3] + bb[3]};
    *(float4*)&C[(size_t)(i0 + ty * 4 + m) * ldc + j0 + tx * 4] = st;
  }
}

// ---------------- u_i = K_i . Wq[:,H], v_i = K_i . bq  (one wave per row) ---------
__global__ __launch_bounds__(64) void uv_k(const float* __restrict__ Kmat,
                                           const float* __restrict__ Wq,
                                           const float* __restrict__ bq,
                                           float* __restrict__ u, float* __restrict__ v) {
  int i = blockIdx.x;
  int lane = threadIdx.x;
  float su = 0.f, sv = 0.f;
#pragma unroll
  for (int m = 0; m < HH / 64; ++m) {
    int j = lane + 64 * m;
    float kv = Kmat[(size_t)i * HH + j];
    su = fmaf(kv, Wq[(size_t)j * (HH + 2) + HH], su);
    sv = fmaf(kv, bq[j], sv);
  }
#pragma unroll
  for (int off = 32; off; off >>= 1) {
    su += __shfl_down(su, off, 64);
    sv += __shfl_down(sv, off, 64);
  }
  if (lane == 0) { u[i] = su; v[i] = sv; }
}

// ---------------- umax = max |u| ----------------
__global__ __launch_bounds__(256) void umax_k(const float* __restrict__ u,
                                              float* __restrict__ umaxp) {
  __shared__ float sm[256];
  int t = threadIdx.x;
  float m = 0.f;
  for (int i = t; i < NN; i += 256) m = fmaxf(m, fabsf(u[i]));
  sm[t] = m;
  __syncthreads();
  for (int s = 128; s; s >>= 1) {
    if (t < s) sm[t] = fmaxf(sm[t], sm[t + s]);
    __syncthreads();
  }
  if (t == 0) *umaxp = m = sm[0];
}

// ---------------- per-row exact top-KCAND by g: 4-pass radix-select ----------------
__device__ __forceinline__ unsigned f2key(float f) {
  unsigned x = __float_as_uint(f);
  return x ^ ((x >> 31) ? 0xFFFFFFFFu : 0x80000000u);  // monotonic asc mapping
}
__device__ __forceinline__ float key2f(unsigned k) {
  unsigned x = (k & 0x80000000u) ? (k ^ 0x80000000u) : ~k;
  return __uint_as_float(x);
}
__global__ __launch_bounds__(256) void prep_cand(const float* __restrict__ GT,
                                                 uint2* __restrict__ cand,
                                                 float* __restrict__ thr) {
  __shared__ float rowv[NN];
  __shared__ int hist[256];
  __shared__ int s_d, s_need, s_gt, s_eq;
  const int row = blockIdx.x, t = threadIdx.x;
  for (int i = t; i < NN; i += 256) rowv[i] = GT[(size_t)row * NN + i];
  __syncthreads();
  unsigned prefix = 0;
  int need = KCAND;
  for (int pass = 0; pass < 4; ++pass) {
    hist[t] = 0;
    __syncthreads();
    const int shift = 24 - 8 * pass;
    for (int i = t; i < NN; i += 256) {
      unsigned k = f2key(rowv[i]);
      if (pass == 0 || (k >> (shift + 8)) == (prefix >> (shift + 8)))
        atomicAdd(&hist[(k >> shift) & 0xFF], 1);
    }
    __syncthreads();
    if (t == 0) {
      int cum = 0, d = 255;
      for (; d > 0; --d) {
        if (cum + hist[d] >= need) break;
        cum += hist[d];
      }
      s_d = d;
      s_need = need - cum;  // how many to take from digit d at next level
    }
    __syncthreads();
    prefix |= ((unsigned)s_d) << shift;
    need = s_need;
    __syncthreads();
  }
  const unsigned thrk = prefix;  // exact KCAND-th largest key
  if (t == 0) { s_gt = 0; s_eq = 0; thr[row] = key2f(thrk); }
  __syncthreads();
  for (int i = t; i < NN; i += 256) {
    if (f2key(rowv[i]) > thrk) {
      int p = atomicAdd(&s_gt, 1);
      cand[(size_t)row * KCAND + p] = make_uint2(__float_as_uint(rowv[i]), (unsigned)i);
    }
  }
  __syncthreads();
  const int cgt = s_gt;  // count(> thr) == KCAND - need_final
  for (int i = t; i < NN; i += 256) {
    if (f2key(rowv[i]) == thrk) {
      int p = atomicAdd(&s_eq, 1);
      if (p < KCAND - cgt)
        cand[(size_t)row * KCAND + cgt + p] = make_uint2(__float_as_uint(rowv[i]), (unsigned)i);
    }
  }
}

// DPP merge of (bv,bi): max value, smallest index on ties. Invalid lanes get
// (-inf, INT_MAX).
#define DPP_MERGE2(CTRL)                                                      \
  {                                                                           \
    int ovb = __builtin_amdgcn_update_dpp(                                    \
        (int)0xFF800000, __float_as_int(bv), (CTRL), 0xf, 0xf, false);        \
    int oib = __builtin_amdgcn_update_dpp(                                    \
        0x7fffffff, bi, (CTRL), 0xf, 0xf, false);                             \
    float ov = __int_as_float(ovb);                                           \
    if (ov > bv || (ov == bv && oib < bi)) { bv = ov; bi = oib; }             \
  }

// ---------------- sequential decode: ONE wave ------------------------------------
// Fast path: 4 candidates/lane from the top-256 list (16 lines). Fallback:
// R5-verbatim full-row scan (64 lines). No barriers in the step loop.
__global__ __launch_bounds__(64, 1) void decode(const float* __restrict__ GT,
                                                const uint2* __restrict__ cand,
                                                const float* __restrict__ thrp,
                                                const float* __restrict__ umaxp,
                                                const float* __restrict__ u,
                                                const float* __restrict__ demands,
                                                const int* __restrict__ capp,
                                                const int* __restrict__ depotp,
                                                float* __restrict__ out) {
  __shared__ __align__(16) float s_dem[NN];   // raw demands
  __shared__ __align__(16) float s_dd[NN];    // demands, +inf when visited
  __shared__ __align__(16) float s_u[NN];     // u_i (for candidate gather)
  __shared__ __align__(16) uint4 s_dcand[KCAND / 2];  // depot candidate list
  __shared__ __align__(16) float s_tour[TSTEPS + 1];
  __shared__ __align__(16) float s_lr[TSTEPS];  // lr per step; -1 => score 0

  const int lane = threadIdx.x;
  const int depot = *depotp;
  const float capf = (float)(*capp);
  const float umaxv = *umaxp;
  const float INF = __builtin_inff();
  const float NEGINF = -INF;
  const float C0 = 0.015625f;   // ALPHA / sqrt(HID), exact power of two
  const float MARGIN = 0.5f;    // >> any fp32 rounding in the bound

  for (int i = lane; i < NN; i += 64) {
    float d = demands[i];
    s_dem[i] = d;
    s_dd[i] = d;
    s_u[i] = u[i];
  }
  const uint4* dc4 = (const uint4*)(cand + (size_t)depot * KCAND);
  for (int i = lane; i < KCAND / 2; i += 64) s_dcand[i] = dc4[i];
  const float thrd = thrp[depot];
  __syncthreads();
  if (lane == 0) {
    s_dd[depot] = INF;  // depot starts visited
    s_tour[0] = (float)depot;
  }

  float uu[32];  // R5 layout for the fallback scan: uu[r*4+j] = u[4*(r*64+lane)+j]
#pragma unroll
  for (int r = 0; r < 8; ++r) {
    float4 u4 = ((const float4*)u)[r * 64 + lane];
    uu[r * 4 + 0] = u4.x; uu[r * 4 + 1] = u4.y;
    uu[r * 4 + 2] = u4.z; uu[r * 4 + 3] = u4.w;
  }

  const float4* dd4 = (const float4*)s_dd;

  int done = 0, ntaken = 0, lasts = depot;
  float load = capf;
  float lr = load / capf;  // same fp32 division as reference
  float thrcur = thrd;
  uint4 ca = dc4[lane], cb = dc4[64 + lane];  // step-0 candidates (global; warm)

  for (int step = 0; step < TSTEPS; ++step) {
    if (done) {  // ref emits (depot, 0) forever once done
      const float df = (float)depot;
      for (int q = step + lane; q < TSTEPS; q += 64) {
        s_tour[1 + q] = df;
        s_lr[q] = -1.0f;
      }
      break;
    }
    // ---- fast path: evaluate 4 candidates (g is a bit-copy of GT[last][idx])
    float bv = NEGINF;
    int bi = 0x7fffffff;
#pragma unroll
    for (int q = 0; q < 2; ++q) {
      const uint4 c4 = q ? cb : ca;
      float g0 = __uint_as_float(c4.x); int i0 = (int)c4.y;
      float g1 = __uint_as_float(c4.z); int i1 = (int)c4.w;
      float d0 = s_dd[i0], u0 = s_u[i0];
      float d1 = s_dd[i1], u1 = s_u[i1];
      float t0 = fmaf(u0, lr, g0);  // identical expression to the full scan
      float t1 = fmaf(u1, lr, g1);
      if ((d0 <= load) && (t0 > bv || (t0 == bv && i0 < bi))) { bv = t0; bi = i0; }
      if ((d1 <= load) && (t1 > bv || (t1 == bv && i1 < bi))) { bv = t1; bi = i1; }
    }
    DPP_MERGE2(0x111); DPP_MERGE2(0x112); DPP_MERGE2(0x114);
    DPP_MERGE2(0x118); DPP_MERGE2(0x142); DPP_MERGE2(0x143);
    float rbv = __int_as_float(__builtin_amdgcn_readlane(__float_as_int(bv), 63));
    int rbi = __builtin_amdgcn_readlane(bi, 63);

    // certification: any node outside the list has g <= thr, |u| <= umax
    const float B = fmaf(lr, umaxv, thrcur) + MARGIN;
    int take, nxt;
    if (rbv > B) {  // certified global argmax (no outside node can tie/beat)
      take = 1; nxt = rbi;
    } else {
      // ---- fallback: R5-verbatim exact full-row scan
      const float4* rowp = (const float4*)(GT + (size_t)lasts * NN);
      float bv = NEGINF;
      int bi = NN;
#pragma unroll
      for (int r = 0; r < 8; ++r) {
        float4 g4 = rowp[r * 64 + lane];
        float4 d4 = dd4[r * 64 + lane];
        float gl[4] = {g4.x, g4.y, g4.z, g4.w};
        float dl[4] = {d4.x, d4.y, d4.z, d4.w};
        float cv = NEGINF;
        int cj = 0;
#pragma unroll
        for (int j = 0; j < 4; ++j) {
          float tt = fmaf(uu[r * 4 + j], lr, gl[j]);
          bool feas = (dl[j] <= load);
          if (feas && tt > cv) { cv = tt; cj = j; }
        }
        if (cv > bv) { bv = cv; bi = 4 * (r * 64 + lane) + cj; }  // asc r: first-max
      }
      DPP_MERGE2(0x111); DPP_MERGE2(0x112); DPP_MERGE2(0x114);
      DPP_MERGE2(0x118); DPP_MERGE2(0x142); DPP_MERGE2(0x143);
      float fbv = __int_as_float(__builtin_amdgcn_readlane(__float_as_int(bv), 63));
      rbi = __builtin_amdgcn_readlane(bi, 63);
      take = (fbv > NEGINF);
      nxt = take ? rbi : depot;
    }

    // ---- prefetch next candidate list FIRST (bookkeeping hides under it)
    if (nxt == depot) {
      ca = s_dcand[lane]; cb = s_dcand[64 + lane];
      thrcur = thrd;
    } else {
      const uint4* rc4 = (const uint4*)(cand + (size_t)nxt * KCAND);
      ca = rc4[lane]; cb = rc4[64 + lane];
      thrcur = thrp[nxt];
    }

    // ---- state update + LDS-buffered outputs
    if (lane == 0) {
      s_tour[1 + step] = (float)nxt;
      s_lr[step] = take ? lr : -1.0f;
    }
    if (take) {
      load = load - s_dem[rbi];  // same fp32 op sequence as reference
      ntaken++;
      if (lane == 0) s_dd[rbi] = INF;
    } else {
      load = capf;
      if (ntaken == NN - 1) done = 1;
    }
    lasts = nxt;
    lr = load / capf;  // same fp32 division as reference
  }

  // ---- flush tour; compute scores exactly in a parallel deferred pass
  for (int i = lane; i <= TSTEPS; i += 64) out[i] = s_tour[i];
  for (int s = lane; s < TSTEPS; s += 64) {
    float lrs = s_lr[s];
    float sc = 0.0f;
    if (lrs >= 0.0f) {
      int lastI = (int)s_tour[s];
      int biI = (int)s_tour[s + 1];
      float g = GT[(size_t)lastI * NN + biI];
      sc = fmaf(u[biI], lrs, g) * C0;  // identical expression to R3-R7
    }
    out[1 + TSTEPS + s] = sc;
  }
}

extern "C" void kernel_launch(void* const* d_in, const int* in_sizes, int n_in,
                              void* d_out, int out_size, void* d_ws, size_t ws_size,
                              hipStream_t stream) {
  const float* emb     = (const float*)d_in[0];  // [N, H]
  const float* demands = (const float*)d_in[1];  // [N]
  const float* Wq      = (const float*)d_in[2];  // [H, H+2]
  const float* bq      = (const float*)d_in[3];  // [H]
  const float* Wk      = (const float*)d_in[4];  // [H, H]
  const float* bk      = (const float*)d_in[5];  // [H]
  const int* cap       = (const int*)d_in[6];
  const int* depot     = (const int*)d_in[7];
  float* out           = (float*)d_out;          // 2305 tour + 2304 scores, fp32

  char* ws = (char*)d_ws;
  float* Kmat = (float*)(ws);                         // 8 MB  [N,H]
  float* Z    = (float*)(ws + ((size_t)8 << 20));     // 8 MB  [N,H]
  float* GT   = (float*)(ws + ((size_t)16 << 20));    // 16 MB [N,N] row=last, +v
  float* Wqh  = (float*)(ws + ((size_t)32 << 20));    // 4 MB  [H,H]; later = cand
  float* u    = (float*)(ws + ((size_t)36 << 20));    // 8 KB
  float* v    = (float*)(ws + ((size_t)36 << 20) + 8192);
  float* thr  = (float*)(ws + ((size_t)36 << 20) + 16384);  // 8 KB
  float* umax = (float*)(ws + ((size_t)36 << 20) + 24576);
  uint2* cnd  = (uint2*)Wqh;  // 4 MB = 2048*256*8 B; Wqh dead after Z GEMM

  hipLaunchKernelGGL(prep_wqh, dim3(4096), dim3(256), 0, stream, Wq, Wqh);
  // K = emb @ Wk^T + bk
  hipLaunchKernelGGL(gemm_nt, dim3(HH / TILE, NN / TILE), dim3(256), 0, stream,
                     emb, HH, Wk, HH, Kmat, HH, HH, bk);
  // Z = emb @ Wqh^T
  hipLaunchKernelGGL(gemm_nt, dim3(HH / TILE, NN / TILE), dim3(256), 0, stream,
                     emb, HH, Wqh, HH, Z, HH, HH, (const float*)nullptr);
  // u_i = K_i . Wq[:,H], v_i = K_i . bq
  hipLaunchKernelGGL(uv_k, dim3(NN), dim3(64), 0, stream, Kmat, Wq, bq, u, v);
  hipLaunchKernelGGL(umax_k, dim3(1), dim3(256), 0, stream, u, umax);
  // GT = Z @ K^T + v (v==0 since bq==0 -> bit-identical)
  hipLaunchKernelGGL(gemm_nt, dim3(NN / TILE, NN / TILE), dim3(256), 0, stream,
                     Z, HH, Kmat, HH, GT, NN, HH, v);
  // top-256 candidate lists (overlays Wqh, which is dead now)
  hipLaunchKernelGGL(prep_cand, dim3(NN), dim3(256), 0, stream, GT, cnd, thr);
  hipLaunchKernelGGL(decode, dim3(1), dim3(64), 0, stream, GT, cnd, thr, umax,
                     u, demands, cap, depot, out);
}

// Round 9
// 2046.106 us; speedup vs baseline: 3.4744x; 1.1759x over previous
//
#include <hip/hip_runtime.h>
#include <hip/hip_bf16.h>

// BeamDecoder: greedy CVRP-style decode.
// s_i(step) = c*( G[last,i] + (load/cap)*u_i )   (v==0 since bq==0; folded)
// R9: R8 (top-256 certified candidate lists) matched prediction (2.0 ms
// decode, FETCH 8.2->2.4 MB, fallback rate low). Two levers on the same
// structure: (1) K=128 -> 16 lines/step (halves line-service ~350 cyc);
// (2) L2 pre-warm kernel: cand (2 MB) + thr fit per-XCD L2 (4 MB); 128
// blocks read them from every XCD right before decode -> per-step dependent
// load LLC(~600cyc) -> L2(~225cyc) if L2 survives the dispatch boundary.
// Certified-exact selection identical to R8: winner among top-K with
// t > thr + lr*umax + 0.5 is provably the global argmax; else verbatim
// R5 full-row scan. Scores exact via deferred pass.

#define NN 2048
#define HH 1024
#define TSTEPS (NN + NN / 8)   // 2304
#define TILE 64
#define KT 16
#define KCAND 128

// ---------------- pack Wq[:, :H] into ld=1024 buffer ----------------
__global__ __launch_bounds__(256) void prep_wqh(const float* __restrict__ Wq,
                                                float* __restrict__ Wqh) {
  int id = blockIdx.x * 256 + threadIdx.x;
  int r = id >> 10, c = id & 1023;
  Wqh[id] = Wq[r * (HH + 2) + c];
}

// ---------------- NT GEMM: C[M,N] = A[M,K] @ B[N,K]^T (+ bias[n]) ----------------
__global__ __launch_bounds__(256) void gemm_nt(const float* __restrict__ A, int lda,
                                               const float* __restrict__ B, int ldb,
                                               float* __restrict__ C, int ldc,
                                               int K, const float* __restrict__ bias) {
  __shared__ float As[KT][TILE + 4];
  __shared__ float Bs[KT][TILE + 4];
  const int i0 = blockIdx.y * TILE;
  const int j0 = blockIdx.x * TILE;
  const int t = threadIdx.x;
  const int srow = t >> 2, sq = t & 3;
  const int tx = t & 15, ty = t >> 4;
  float acc[4][4] = {};
  for (int k0 = 0; k0 < K; k0 += KT) {
    float4 av = *(const float4*)&A[(size_t)(i0 + srow) * lda + k0 + sq * 4];
    float4 bv = *(const float4*)&B[(size_t)(j0 + srow) * ldb + k0 + sq * 4];
    __syncthreads();
    As[sq * 4 + 0][srow] = av.x; As[sq * 4 + 1][srow] = av.y;
    As[sq * 4 + 2][srow] = av.z; As[sq * 4 + 3][srow] = av.w;
    Bs[sq * 4 + 0][srow] = bv.x; Bs[sq * 4 + 1][srow] = bv.y;
    Bs[sq * 4 + 2][srow] = bv.z; Bs[sq * 4 + 3][srow] = bv.w;
    __syncthreads();
#pragma unroll
    for (int k = 0; k < KT; ++k) {
      float4 a4 = *(const float4*)&As[k][ty * 4];
      float4 b4 = *(const float4*)&Bs[k][tx * 4];
      float a[4] = {a4.x, a4.y, a4.z, a4.w};
      float b[4] = {b4.x, b4.y, b4.z, b4.w};
#pragma unroll
      for (int m = 0; m < 4; ++m)
#pragma unroll
        for (int n = 0; n < 4; ++n) acc[m][n] = fmaf(a[m], b[n], acc[m][n]);
    }
  }
  float bb[4] = {0.f, 0.f, 0.f, 0.f};
  if (bias) {
#pragma unroll
    for (int n = 0; n < 4; ++n) bb[n] = bias[j0 + tx * 4 + n];
  }
#pragma unroll
  for (int m = 0; m < 4; ++m) {
    float4 st = {acc[m][0] + bb[0], acc[m][1] + bb[1], acc[m][2] + bb[2], acc[m][3] + bb[3]};
    *(float4*)&C[(size_t)(i0 + ty * 4 + m) * ldc + j0 + tx * 4] = st;
  }
}

// ---------------- u_i = K_i . Wq[:,H], v_i = K_i . bq  (one wave per row) ---------
__global__ __launch_bounds__(64) void uv_k(const float* __restrict__ Kmat,
                                           const float* __restrict__ Wq,
                                           const float* __restrict__ bq,
                                           float* __restrict__ u, float* __restrict__ v) {
  int i = blockIdx.x;
  int lane = threadIdx.x;
  float su = 0.f, sv = 0.f;
#pragma unroll
  for (int m = 0; m < HH / 64; ++m) {
    int j = lane + 64 * m;
    float kv = Kmat[(size_t)i * HH + j];
    su = fmaf(kv, Wq[(size_t)j * (HH + 2) + HH], su);
    sv = fmaf(kv, bq[j], sv);
  }
#pragma unroll
  for (int off = 32; off; off >>= 1) {
    su += __shfl_down(su, off, 64);
    sv += __shfl_down(sv, off, 64);
  }
  if (lane == 0) { u[i] = su; v[i] = sv; }
}

// ---------------- umax = max |u| ----------------
__global__ __launch_bounds__(256) void umax_k(const float* __restrict__ u,
                                              float* __restrict__ umaxp) {
  __shared__ float sm[256];
  int t = threadIdx.x;
  float m = 0.f;
  for (int i = t; i < NN; i += 256) m = fmaxf(m, fabsf(u[i]));
  sm[t] = m;
  __syncthreads();
  for (int s = 128; s; s >>= 1) {
    if (t < s) sm[t] = fmaxf(sm[t], sm[t + s]);
    __syncthreads();
  }
  if (t == 0) *umaxp = sm[0];
}

// ---------------- per-row exact top-KCAND by g: 4-pass radix-select ----------------
__device__ __forceinline__ unsigned f2key(float f) {
  unsigned x = __float_as_uint(f);
  return x ^ ((x >> 31) ? 0xFFFFFFFFu : 0x80000000u);  // monotonic asc mapping
}
__device__ __forceinline__ float key2f(unsigned k) {
  unsigned x = (k & 0x80000000u) ? (k ^ 0x80000000u) : ~k;
  return __uint_as_float(x);
}
__global__ __launch_bounds__(256) void prep_cand(const float* __restrict__ GT,
                                                 uint2* __restrict__ cand,
                                                 float* __restrict__ thr) {
  __shared__ float rowv[NN];
  __shared__ int hist[256];
  __shared__ int s_d, s_need, s_gt, s_eq;
  const int row = blockIdx.x, t = threadIdx.x;
  for (int i = t; i < NN; i += 256) rowv[i] = GT[(size_t)row * NN + i];
  __syncthreads();
  unsigned prefix = 0;
  int need = KCAND;
  for (int pass = 0; pass < 4; ++pass) {
    hist[t] = 0;
    __syncthreads();
    const int shift = 24 - 8 * pass;
    for (int i = t; i < NN; i += 256) {
      unsigned k = f2key(rowv[i]);
      if (pass == 0 || (k >> (shift + 8)) == (prefix >> (shift + 8)))
        atomicAdd(&hist[(k >> shift) & 0xFF], 1);
    }
    __syncthreads();
    if (t == 0) {
      int cum = 0, d = 255;
      for (; d > 0; --d) {
        if (cum + hist[d] >= need) break;
        cum += hist[d];
      }
      s_d = d;
      s_need = need - cum;
    }
    __syncthreads();
    prefix |= ((unsigned)s_d) << shift;
    need = s_need;
    __syncthreads();
  }
  const unsigned thrk = prefix;  // exact KCAND-th largest key
  if (t == 0) { s_gt = 0; s_eq = 0; thr[row] = key2f(thrk); }
  __syncthreads();
  for (int i = t; i < NN; i += 256) {
    if (f2key(rowv[i]) > thrk) {
      int p = atomicAdd(&s_gt, 1);
      cand[(size_t)row * KCAND + p] = make_uint2(__float_as_uint(rowv[i]), (unsigned)i);
    }
  }
  __syncthreads();
  const int cgt = s_gt;
  for (int i = t; i < NN; i += 256) {
    if (f2key(rowv[i]) == thrk) {
      int p = atomicAdd(&s_eq, 1);
      if (p < KCAND - cgt)
        cand[(size_t)row * KCAND + cgt + p] = make_uint2(__float_as_uint(rowv[i]), (unsigned)i);
    }
  }
}

// ---------------- L2 pre-warm: every XCD pulls cand + thr into its L2 ------------
__global__ __launch_bounds__(256) void warm_k(const float* __restrict__ a, int n,
                                              const float* __restrict__ b, int m,
                                              float* __restrict__ sink) {
  float s = 0.f;
  const float4* a4 = (const float4*)a;
  for (int i = threadIdx.x; i < n / 4; i += 256) {
    float4 x = a4[i];
    s += x.x + x.y + x.z + x.w;
  }
  for (int i = threadIdx.x; i < m; i += 256) s += b[i];
  if (s == 1.2345e-30f) sink[blockIdx.x] = s;  // never true; keeps loads alive
}

// DPP merge of (bv,bi): max value, smallest index on ties. Invalid lanes get
// (-inf, INT_MAX).
#define DPP_MERGE2(CTRL)                                                      \
  {                                                                           \
    int ovb = __builtin_amdgcn_update_dpp(                                    \
        (int)0xFF800000, __float_as_int(bv), (CTRL), 0xf, 0xf, false);        \
    int oib = __builtin_amdgcn_update_dpp(                                    \
        0x7fffffff, bi, (CTRL), 0xf, 0xf, false);                             \
    float ov = __int_as_float(ovb);                                           \
    if (ov > bv || (ov == bv && oib < bi)) { bv = ov; bi = oib; }             \
  }

// ---------------- sequential decode: ONE wave ------------------------------------
// Fast path: 2 candidates/lane from the top-128 list (16 lines). Fallback:
// R5-verbatim full-row scan. No barriers in the step loop.
__global__ __launch_bounds__(64, 1) void decode(const float* __restrict__ GT,
                                                const uint2* __restrict__ cand,
                                                const float* __restrict__ thrp,
                                                const float* __restrict__ umaxp,
                                                const float* __restrict__ u,
                                                const float* __restrict__ demands,
                                                const int* __restrict__ capp,
                                                const int* __restrict__ depotp,
                                                float* __restrict__ out) {
  __shared__ __align__(16) float s_dem[NN];   // raw demands
  __shared__ __align__(16) float s_dd[NN];    // demands, +inf when visited
  __shared__ __align__(16) float s_u[NN];     // u_i (for candidate gather)
  __shared__ __align__(16) uint4 s_dcand[KCAND / 2];  // depot candidate list
  __shared__ __align__(16) float s_tour[TSTEPS + 1];
  __shared__ __align__(16) float s_lr[TSTEPS];  // lr per step; -1 => score 0

  const int lane = threadIdx.x;
  const int depot = *depotp;
  const float capf = (float)(*capp);
  const float umaxv = *umaxp;
  const float INF = __builtin_inff();
  const float NEGINF = -INF;
  const float C0 = 0.015625f;   // ALPHA / sqrt(HID), exact power of two
  const float MARGIN = 0.5f;    // >> any fp32 rounding in the bound

  for (int i = lane; i < NN; i += 64) {
    float d = demands[i];
    s_dem[i] = d;
    s_dd[i] = d;
    s_u[i] = u[i];
  }
  const uint4* dc4 = (const uint4*)(cand + (size_t)depot * KCAND);
  for (int i = lane; i < KCAND / 2; i += 64) s_dcand[i] = dc4[i];
  const float thrd = thrp[depot];
  __syncthreads();
  if (lane == 0) {
    s_dd[depot] = INF;  // depot starts visited
    s_tour[0] = (float)depot;
  }

  float uu[32];  // R5 layout for the fallback scan: uu[r*4+j] = u[4*(r*64+lane)+j]
#pragma unroll
  for (int r = 0; r < 8; ++r) {
    float4 u4 = ((const float4*)u)[r * 64 + lane];
    uu[r * 4 + 0] = u4.x; uu[r * 4 + 1] = u4.y;
    uu[r * 4 + 2] = u4.z; uu[r * 4 + 3] = u4.w;
  }

  const float4* dd4 = (const float4*)s_dd;

  int done = 0, ntaken = 0, lasts = depot;
  float load = capf;
  float lr = load / capf;  // same fp32 division as reference
  float thrcur = thrd;
  uint4 ca = dc4[lane];    // step-0 candidates

  for (int step = 0; step < TSTEPS; ++step) {
    if (done) {  // ref emits (depot, 0) forever once done
      const float df = (float)depot;
      for (int q = step + lane; q < TSTEPS; q += 64) {
        s_tour[1 + q] = df;
        s_lr[q] = -1.0f;
      }
      break;
    }
    // ---- fast path: evaluate 2 candidates (g is a bit-copy of GT[last][idx])
    float bv = NEGINF;
    int bi = 0x7fffffff;
    {
      float g0 = __uint_as_float(ca.x); int i0 = (int)ca.y;
      float g1 = __uint_as_float(ca.z); int i1 = (int)ca.w;
      float d0 = s_dd[i0], u0 = s_u[i0];
      float d1 = s_dd[i1], u1 = s_u[i1];
      float t0 = fmaf(u0, lr, g0);  // identical expression to the full scan
      float t1 = fmaf(u1, lr, g1);
      if ((d0 <= load) && (t0 > bv || (t0 == bv && i0 < bi))) { bv = t0; bi = i0; }
      if ((d1 <= load) && (t1 > bv || (t1 == bv && i1 < bi))) { bv = t1; bi = i1; }
    }
    DPP_MERGE2(0x111); DPP_MERGE2(0x112); DPP_MERGE2(0x114);
    DPP_MERGE2(0x118); DPP_MERGE2(0x142); DPP_MERGE2(0x143);
    float rbv = __int_as_float(__builtin_amdgcn_readlane(__float_as_int(bv), 63));
    int rbi = __builtin_amdgcn_readlane(bi, 63);

    // certification: any node outside the list has g <= thr, |u| <= umax
    const float B = fmaf(lr, umaxv, thrcur) + MARGIN;
    int take, nxt;
    if (rbv > B) {  // certified global argmax (no outside node can tie/beat)
      take = 1; nxt = rbi;
    } else {
      // ---- fallback: R5-verbatim exact full-row scan
      const float4* rowp = (const float4*)(GT + (size_t)lasts * NN);
      float bv = NEGINF;
      int bi = NN;
#pragma unroll
      for (int r = 0; r < 8; ++r) {
        float4 g4 = rowp[r * 64 + lane];
        float4 d4 = dd4[r * 64 + lane];
        float gl[4] = {g4.x, g4.y, g4.z, g4.w};
        float dl[4] = {d4.x, d4.y, d4.z, d4.w};
        float cv = NEGINF;
        int cj = 0;
#pragma unroll
        for (int j = 0; j < 4; ++j) {
          float tt = fmaf(uu[r * 4 + j], lr, gl[j]);
          bool feas = (dl[j] <= load);
          if (feas && tt > cv) { cv = tt; cj = j; }
        }
        if (cv > bv) { bv = cv; bi = 4 * (r * 64 + lane) + cj; }  // asc r: first-max
      }
      DPP_MERGE2(0x111); DPP_MERGE2(0x112); DPP_MERGE2(0x114);
      DPP_MERGE2(0x118); DPP_MERGE2(0x142); DPP_MERGE2(0x143);
      float fbv = __int_as_float(__builtin_amdgcn_readlane(__float_as_int(bv), 63));
      rbi = __builtin_amdgcn_readlane(bi, 63);
      take = (fbv > NEGINF);
      nxt = take ? rbi : depot;
    }

    // ---- prefetch next candidate list FIRST (bookkeeping hides under it)
    if (nxt == depot) {
      ca = s_dcand[lane];
      thrcur = thrd;
    } else {
      const uint4* rc4 = (const uint4*)(cand + (size_t)nxt * KCAND);
      ca = rc4[lane];
      thrcur = thrp[nxt];
    }

    // ---- state update + LDS-buffered outputs
    if (lane == 0) {
      s_tour[1 + step] = (float)nxt;
      s_lr[step] = take ? lr : -1.0f;
    }
    if (take) {
      load = load - s_dem[rbi];  // same fp32 op sequence as reference
      ntaken++;
      if (lane == 0) s_dd[rbi] = INF;
    } else {
      load = capf;
      if (ntaken == NN - 1) done = 1;
    }
    lasts = nxt;
    lr = load / capf;  // same fp32 division as reference
  }

  // ---- flush tour; compute scores exactly in a parallel deferred pass
  for (int i = lane; i <= TSTEPS; i += 64) out[i] = s_tour[i];
  for (int s = lane; s < TSTEPS; s += 64) {
    float lrs = s_lr[s];
    float sc = 0.0f;
    if (lrs >= 0.0f) {
      int lastI = (int)s_tour[s];
      int biI = (int)s_tour[s + 1];
      float g = GT[(size_t)lastI * NN + biI];
      sc = fmaf(u[biI], lrs, g) * C0;  // identical expression to R3-R8
    }
    out[1 + TSTEPS + s] = sc;
  }
}

extern "C" void kernel_launch(void* const* d_in, const int* in_sizes, int n_in,
                              void* d_out, int out_size, void* d_ws, size_t ws_size,
                              hipStream_t stream) {
  const float* emb     = (const float*)d_in[0];  // [N, H]
  const float* demands = (const float*)d_in[1];  // [N]
  const float* Wq      = (const float*)d_in[2];  // [H, H+2]
  const float* bq      = (const float*)d_in[3];  // [H]
  const float* Wk      = (const float*)d_in[4];  // [H, H]
  const float* bk      = (const float*)d_in[5];  // [H]
  const int* cap       = (const int*)d_in[6];
  const int* depot     = (const int*)d_in[7];
  float* out           = (float*)d_out;          // 2305 tour + 2304 scores, fp32

  char* ws = (char*)d_ws;
  float* Kmat = (float*)(ws);                         // 8 MB  [N,H]
  float* Z    = (float*)(ws + ((size_t)8 << 20));     // 8 MB  [N,H]
  float* GT   = (float*)(ws + ((size_t)16 << 20));    // 16 MB [N,N] row=last, +v
  float* Wqh  = (float*)(ws + ((size_t)32 << 20));    // 4 MB  [H,H]; later = cand
  float* u    = (float*)(ws + ((size_t)36 << 20));    // 8 KB
  float* v    = (float*)(ws + ((size_t)36 << 20) + 8192);
  float* thr  = (float*)(ws + ((size_t)36 << 20) + 16384);  // 8 KB
  float* umax = (float*)(ws + ((size_t)36 << 20) + 24576);
  float* sink = (float*)(ws + ((size_t)36 << 20) + 32768);  // warm sink (unused)
  uint2* cnd  = (uint2*)Wqh;  // 2 MB = 2048*128*8 B; Wqh dead after Z GEMM

  hipLaunchKernelGGL(prep_wqh, dim3(4096), dim3(256), 0, stream, Wq, Wqh);
  // K = emb @ Wk^T + bk
  hipLaunchKernelGGL(gemm_nt, dim3(HH / TILE, NN / TILE), dim3(256), 0, stream,
                     emb, HH, Wk, HH, Kmat, HH, HH, bk);
  // Z = emb @ Wqh^T
  hipLaunchKernelGGL(gemm_nt, dim3(HH / TILE, NN / TILE), dim3(256), 0, stream,
                     emb, HH, Wqh, HH, Z, HH, HH, (const float*)nullptr);
  // u_i = K_i . Wq[:,H], v_i = K_i . bq
  hipLaunchKernelGGL(uv_k, dim3(NN), dim3(64), 0, stream, Kmat, Wq, bq, u, v);
  hipLaunchKernelGGL(umax_k, dim3(1), dim3(256), 0, stream, u, umax);
  // GT = Z @ K^T + v (v==0 since bq==0 -> bit-identical)
  hipLaunchKernelGGL(gemm_nt, dim3(NN / TILE, NN / TILE), dim3(256), 0, stream,
                     Z, HH, Kmat, HH, GT, NN, HH, v);
  // top-128 candidate lists (overlays Wqh, which is dead now)
  hipLaunchKernelGGL(prep_cand, dim3(NN), dim3(256), 0, stream, GT, cnd, thr);
  // pre-warm every XCD's L2 with cand (2 MB) + thr
  hipLaunchKernelGGL(warm_k, dim3(128), dim3(256), 0, stream,
                     (const float*)cnd, NN * KCAND * 2, thr, NN, sink);
  hipLaunchKernelGGL(decode, dim3(1), dim3(64), 0, stream, GT, cnd, thr, umax,
                     u, demands, cap, depot, out);
}